// Round 1
// baseline (830.349 us; speedup 1.0000x reference)
//
#include <hip/hip_runtime.h>

// entmax-1.5 along last dim, d = 1024.
// One 64-lane wave per row; 16 elements/lane held in registers (4x float4).
// tau solved by Newton on f(tau) = sum max(x/2 - tau, 0)^2 = 1 (convex,
// monotone decreasing; start tau = xmax - 1 where f >= 1 => monotone
// convergence from the left, no sort needed).

constexpr int D = 1024;
constexpr int WAVES_PER_BLOCK = 4; // 256 threads

__global__ __launch_bounds__(256) void entmax15_kernel(const float* __restrict__ x,
                                                       float* __restrict__ y,
                                                       int nrows) {
    const int wave = threadIdx.x >> 6;
    const int lane = threadIdx.x & 63;
    const int row  = blockIdx.x * WAVES_PER_BLOCK + wave;
    if (row >= nrows) return;

    const float4* xr = (const float4*)(x + (size_t)row * D);
    float4*       yr = (float4*)(y + (size_t)row * D);

    // Coalesced load: lane i takes float4 #(i + 64*j), j = 0..3  -> 1024 floats.
    float4 v[4];
#pragma unroll
    for (int j = 0; j < 4; ++j) v[j] = xr[lane + 64 * j];

    // x <- x/2 ; row max
    float m = -3.4e38f;
#pragma unroll
    for (int j = 0; j < 4; ++j) {
        v[j].x *= 0.5f; v[j].y *= 0.5f; v[j].z *= 0.5f; v[j].w *= 0.5f;
        m = fmaxf(m, fmaxf(fmaxf(v[j].x, v[j].y), fmaxf(v[j].z, v[j].w)));
    }
#pragma unroll
    for (int off = 32; off >= 1; off >>= 1) m = fmaxf(m, __shfl_xor(m, off));

#pragma unroll
    for (int j = 0; j < 4; ++j) { v[j].x -= m; v[j].y -= m; v[j].z -= m; v[j].w -= m; }

    // Newton: f(tau) = sum max(x - tau, 0)^2 ; f' = -2 * sum max(x - tau, 0).
    // Start at tau = xmax - 1 = -1 (f(-1) >= 1). Converges monotonically up.
    float tau = -1.0f;
    for (int it = 0; it < 50; ++it) {
        float s1 = 0.f, s2 = 0.f;
#pragma unroll
        for (int j = 0; j < 4; ++j) {
            float t;
            t = fmaxf(v[j].x - tau, 0.f); s1 += t; s2 = fmaf(t, t, s2);
            t = fmaxf(v[j].y - tau, 0.f); s1 += t; s2 = fmaf(t, t, s2);
            t = fmaxf(v[j].z - tau, 0.f); s1 += t; s2 = fmaf(t, t, s2);
            t = fmaxf(v[j].w - tau, 0.f); s1 += t; s2 = fmaf(t, t, s2);
        }
#pragma unroll
        for (int off = 32; off >= 1; off >>= 1) {
            s1 += __shfl_xor(s1, off);
            s2 += __shfl_xor(s2, off);
        }
        float diff = s2 - 1.0f;          // >= 0 in exact arithmetic
        if (diff <= 1e-7f) break;        // wave-uniform break (s1,s2 uniform)
        float tnew = tau + diff / (2.0f * s1);
        if (tnew == tau) break;          // fp fixed point
        tau = tnew;
    }

    // y = max(x - tau, 0)^2, coalesced float4 stores.
#pragma unroll
    for (int j = 0; j < 4; ++j) {
        float4 o; float t;
        t = fmaxf(v[j].x - tau, 0.f); o.x = t * t;
        t = fmaxf(v[j].y - tau, 0.f); o.y = t * t;
        t = fmaxf(v[j].z - tau, 0.f); o.z = t * t;
        t = fmaxf(v[j].w - tau, 0.f); o.w = t * t;
        yr[lane + 64 * j] = o;
    }
}

extern "C" void kernel_launch(void* const* d_in, const int* in_sizes, int n_in,
                              void* d_out, int out_size, void* d_ws, size_t ws_size,
                              hipStream_t stream) {
    const float* x = (const float*)d_in[0];
    float*       y = (float*)d_out;
    const int nrows = in_sizes[0] / D;              // 131072
    const int blocks = (nrows + WAVES_PER_BLOCK - 1) / WAVES_PER_BLOCK;
    entmax15_kernel<<<blocks, 256, 0, stream>>>(x, y, nrows);
}